// Round 10
// baseline (1611.530 us; speedup 1.0000x reference)
//
#include <hip/hip_runtime.h>
#include <math.h>

#define ROUTIT 6
#define CAP 16   // cached edges per wave: 2 waves * 16 * 64 * 8B = 16 KB/block
#define WPB 2    // waves per block in route_kernel

// ---------------------------------------------------------------------------
// Index dtype detection (harness delivers int indices as int32; reference
// declares int64 — detect which encoding is present at runtime).
// ---------------------------------------------------------------------------
__global__ void detect_idx64_kernel(const int* __restrict__ raw, int* __restrict__ flag)
{
    int all_zero = 1;
    for (int i = 1; i < 64; i += 2)
        if (raw[i] != 0) { all_zero = 0; break; }
    *flag = all_zero;   // 1 => int64 encoding, 0 => int32
}

__device__ __forceinline__ int load_idx(const void* p, long long i, int is64)
{
    if (is64) return (int)((const long long*)p)[i];
    return ((const int*)p)[i];
}

// ---------------------------------------------------------------------------
// Cross-lane reductions on the VALU pipe only (DPP + readlane).
// dpp_add / rowsum16 verified in rounds 8-9. Denominator now uses the classic
// row_bcast15/31 reduce + v_readlane broadcast — NO DS ops, NO permlane asm
// (round-6/7 bug: "+v","+v" asm let regalloc alias both operands -> no-op).
// ---------------------------------------------------------------------------
template <int CTRL>
__device__ __forceinline__ float dpp_add(float x)
{
    int y = __builtin_amdgcn_update_dpp(0, __float_as_int(x), CTRL, 0xf, 0xf, true);
    return x + __int_as_float(y);
}

// sum over the 16-lane row (every lane of the row gets the total)
__device__ __forceinline__ float rowsum16(float p)
{
    p = dpp_add<0xB1>(p);   // quad_perm [1,0,3,2] : xor 1
    p = dpp_add<0x4E>(p);   // quad_perm [2,3,0,1] : xor 2
    p = dpp_add<0x124>(p);  // row_ror:4
    p = dpp_add<0x128>(p);  // row_ror:8
    return p;
}

// total of a row-constant value across the 4 rows, returned uniform (SGPR)
__device__ __forceinline__ float xrow_total(float ex)
{
    float t = dpp_add<0x142>(ex);  // row_bcast15: row1 += r0, row3 += r2
    t = dpp_add<0x143>(t);         // row_bcast31: rows 2,3 += (r0+r1)
    // lanes 48..63 now hold r0+r1+r2+r3
    return __uint_as_float((unsigned)__builtin_amdgcn_readlane(__float_as_uint(t), 63));
}

// per-edge contribution: softmax weight over 4 channels, accumulate
__device__ __forceinline__ void edge_acc(float zx, float zy, float cx, float cy,
                                         float& a0, float& a1)
{
    float p = zx * cx + zy * cy;
    p = rowsum16(p);                    // 32-elem channel dot, |p| <= 1
    float ex = __expf(p);               // no max-subtraction needed
    float d  = xrow_total(ex);          // softmax denom over 4 channels (uniform)
    float w  = ex * __builtin_amdgcn_rcpf(d);
    a0 += w * zx;
    a1 += w * zy;
}

// ---------------------------------------------------------------------------
// GEMM + per-channel L2 normalize (fp32 h).
// v2: x read straight from global (32 lanes/row coalesce to one transaction),
// only W^T staged in LDS, read as b128 -> DS-pipe load cut ~2.7x vs v1.
// ---------------------------------------------------------------------------
__global__ __launch_bounds__(256)
void gemm_norm_kernel(const float* __restrict__ x, const float* __restrict__ W,
                      const float* __restrict__ b, float* __restrict__ h, int n)
{
    __shared__ float WT[32 * 132];    // WT[lc*132 + j] = W[j][l0+lc]

    const int tid  = threadIdx.x;
    const int jc   = tid & 31;        // col group: cols jc*4 .. jc*4+3
    const int rg   = tid >> 5;        // row group: rows rg*4 .. rg*4+3
    const int row0 = blockIdx.x * 32;

    float4 bb = ((const float4*)b)[jc];
    float acc[4][4];
    #pragma unroll
    for (int ri = 0; ri < 4; ++ri) {
        acc[ri][0] = bb.x; acc[ri][1] = bb.y; acc[ri][2] = bb.z; acc[ri][3] = bb.w;
    }

    for (int l0 = 0; l0 < 128; l0 += 32) {
        __syncthreads();
        for (int t = 0; t < 16; ++t) {
            int idx = t * 256 + tid;
            int jj = idx >> 5, lc = idx & 31;
            WT[lc * 132 + jj] = W[jj * 128 + l0 + lc];
        }
        __syncthreads();

        for (int lc = 0; lc < 32; lc += 4) {
            float4 xv[4];
            #pragma unroll
            for (int ri = 0; ri < 4; ++ri) {
                int row = row0 + rg * 4 + ri;
                row = row < n ? row : n - 1;
                xv[ri] = *(const float4*)(x + (size_t)row * 128 + l0 + lc);
            }
            #pragma unroll
            for (int k = 0; k < 4; ++k) {
                float4 wt = ((const float4*)(WT + (lc + k) * 132))[jc];
                #pragma unroll
                for (int ri = 0; ri < 4; ++ri) {
                    float xs = (k == 0) ? xv[ri].x : (k == 1) ? xv[ri].y
                             : (k == 2) ? xv[ri].z : xv[ri].w;
                    acc[ri][0] += xs * wt.x;
                    acc[ri][1] += xs * wt.y;
                    acc[ri][2] += xs * wt.z;
                    acc[ri][3] += xs * wt.w;
                }
            }
        }
    }

    #pragma unroll
    for (int ri = 0; ri < 4; ++ri) {
        float ss = acc[ri][0]*acc[ri][0] + acc[ri][1]*acc[ri][1]
                 + acc[ri][2]*acc[ri][2] + acc[ri][3]*acc[ri][3];
        ss += __shfl_xor(ss, 1);
        ss += __shfl_xor(ss, 2);
        ss += __shfl_xor(ss, 4);
        float inv = 1.0f / fmaxf(sqrtf(ss), 1e-12f);
        int row = row0 + rg * 4 + ri;
        if (row < n) {
            float4 o;
            o.x = acc[ri][0]*inv; o.y = acc[ri][1]*inv;
            o.z = acc[ri][2]*inv; o.w = acc[ri][3]*inv;
            ((float4*)(h + (size_t)row * 128))[jc] = o;
        }
    }
}

// ---------------------------------------------------------------------------
// CSR build
// ---------------------------------------------------------------------------
__global__ void zero_kernel(int* __restrict__ p, int n)
{
    int i = blockIdx.x * blockDim.x + threadIdx.x;
    if (i < n) p[i] = 0;
}

__global__ void hist_kernel(const void* __restrict__ st, long long m, int n,
                            const int* __restrict__ idx64, int* __restrict__ cnt)
{
    long long e = (long long)blockIdx.x * blockDim.x + threadIdx.x;
    if (e < m) {
        int t = load_idx(st, m + e, *idx64);
        if (t >= 0 && t < n) atomicAdd(&cnt[t], 1);
    }
}

__global__ __launch_bounds__(1024)
void scan_kernel(const int* __restrict__ cnt, int n,
                 int* __restrict__ row_ptr, int* __restrict__ cursor)
{
    __shared__ int lds[1024];
    int t = threadIdx.x;
    int per = (n + 1023) / 1024;
    int lo = min(t * per, n), hi = min(lo + per, n);
    int s = 0;
    for (int i = lo; i < hi; ++i) s += cnt[i];
    lds[t] = s;
    __syncthreads();
    for (int off = 1; off < 1024; off <<= 1) {
        int v = (t >= off) ? lds[t - off] : 0;
        __syncthreads();
        lds[t] += v;
        __syncthreads();
    }
    int run = lds[t] - s;
    for (int i = lo; i < hi; ++i) {
        row_ptr[i] = run; cursor[i] = run; run += cnt[i];
    }
    if (t == 0) row_ptr[n] = lds[1023];
}

__global__ void scatter_kernel(const void* __restrict__ st, long long m, int n,
                               const int* __restrict__ idx64,
                               int* __restrict__ cursor, int* __restrict__ edge_src)
{
    long long e = (long long)blockIdx.x * blockDim.x + threadIdx.x;
    if (e < m) {
        int is64 = *idx64;
        int t = load_idx(st, m + e, is64);
        int s = load_idx(st, e, is64);
        if (t >= 0 && t < n) {
            int pos = atomicAdd(&cursor[t], 1);
            edge_src[pos] = s;
        }
    }
}

// ---------------------------------------------------------------------------
// Routing: one wave per node, 6 iterations fused, c in registers (fp32).
// Iter 0 gathers + caches first CAP edges' z-rows in LDS; iters 1..5 replay
// (4-wide unrolled for ILP). Per-edge cross-lane work is all-VALU except one
// ds_read_b64 for the cached z.
// ---------------------------------------------------------------------------
__global__ __launch_bounds__(64 * WPB)
void route_kernel(const float* __restrict__ h, const int* __restrict__ row_ptr,
                  const int* __restrict__ edge_src, float* __restrict__ out, int n)
{
    __shared__ float2 zls[WPB][CAP][64];

    int wv   = threadIdx.x >> 6;
    int wid  = __builtin_amdgcn_readfirstlane(blockIdx.x * WPB + wv);
    int lane = threadIdx.x & 63;
    if (wid >= n) return;

    const float2* __restrict__ h2 = (const float2*)h;
    float2 c0 = h2[(size_t)wid * 64 + lane];
    float cx = c0.x, cy = c0.y;

    const int e0  = row_ptr[wid], e1 = row_ptr[wid + 1];
    const int deg = e1 - e0;
    const int nc  = deg < CAP ? deg : CAP;

    // ---- iteration 0: gather, cache in LDS, compute ----
    float a0 = cx, a1 = cy;
    {
        int j = 0;
        for (; j + 1 < nc; j += 2) {
            int sa = edge_src[e0 + j];
            int sb = edge_src[e0 + j + 1];
            float2 za = h2[(size_t)sa * 64 + lane];
            float2 zb = h2[(size_t)sb * 64 + lane];
            zls[wv][j][lane] = za;
            zls[wv][j + 1][lane] = zb;
            edge_acc(za.x, za.y, cx, cy, a0, a1);
            edge_acc(zb.x, zb.y, cx, cy, a0, a1);
        }
        if (j < nc) {
            int s = edge_src[e0 + j];
            float2 z = h2[(size_t)s * 64 + lane];
            zls[wv][j][lane] = z;
            edge_acc(z.x, z.y, cx, cy, a0, a1);
        }
        for (int e = e0 + nc; e < e1; ++e) {
            int s = edge_src[e];
            float2 z = h2[(size_t)s * 64 + lane];
            edge_acc(z.x, z.y, cx, cy, a0, a1);
        }
        float ss = rowsum16(a0 * a0 + a1 * a1);
        float inv = __builtin_amdgcn_rcpf(fmaxf(sqrtf(ss), 1e-12f));
        cx = a0 * inv; cy = a1 * inv;
    }

    // ---- iterations 1..5: replay from LDS (+ uncached tail), 4-wide ILP ----
    #pragma unroll 1
    for (int it = 1; it < ROUTIT; ++it) {
        a0 = cx; a1 = cy;
        int j = 0;
        for (; j + 3 < nc; j += 4) {
            float2 z0 = zls[wv][j][lane];
            float2 z1 = zls[wv][j + 1][lane];
            float2 z2 = zls[wv][j + 2][lane];
            float2 z3 = zls[wv][j + 3][lane];
            edge_acc(z0.x, z0.y, cx, cy, a0, a1);
            edge_acc(z1.x, z1.y, cx, cy, a0, a1);
            edge_acc(z2.x, z2.y, cx, cy, a0, a1);
            edge_acc(z3.x, z3.y, cx, cy, a0, a1);
        }
        for (; j < nc; ++j) {
            float2 z = zls[wv][j][lane];
            edge_acc(z.x, z.y, cx, cy, a0, a1);
        }
        for (int e = e0 + nc; e < e1; ++e) {
            int s = edge_src[e];
            float2 z = h2[(size_t)s * 64 + lane];
            edge_acc(z.x, z.y, cx, cy, a0, a1);
        }
        float ss = rowsum16(a0 * a0 + a1 * a1);
        float inv = __builtin_amdgcn_rcpf(fmaxf(sqrtf(ss), 1e-12f));
        cx = a0 * inv; cy = a1 * inv;
    }

    float2 o; o.x = cx; o.y = cy;
    ((float2*)out)[(size_t)wid * 64 + lane] = o;
}

// ---------------------------------------------------------------------------
extern "C" void kernel_launch(void* const* d_in, const int* in_sizes, int n_in,
                              void* d_out, int out_size, void* d_ws, size_t ws_size,
                              hipStream_t stream)
{
    const float* x       = (const float*)d_in[0];
    const void*  src_trg = d_in[1];
    const float* W       = (const float*)d_in[2];
    const float* b       = (const float*)d_in[3];
    float*       out     = (float*)d_out;

    int n = in_sizes[0] / 128;
    long long m = in_sizes[1] / 2;

    // workspace layout (~59 MB)
    float* h        = (float*)d_ws;                    // n*128 floats (51.2 MB)
    int*   cnt      = (int*)(h + (size_t)n * 128);     // n
    int*   row_ptr  = cnt + n;                         // n+1
    int*   cursor   = row_ptr + (n + 1);               // n
    int*   edge_src = cursor + n;                      // m ints (6.4 MB)
    int*   idx64    = edge_src + m;                    // 1 flag

    hipLaunchKernelGGL(detect_idx64_kernel, dim3(1), dim3(1), 0, stream,
                       (const int*)src_trg, idx64);
    hipLaunchKernelGGL(gemm_norm_kernel, dim3((n + 31) / 32), dim3(256), 0, stream,
                       x, W, b, h, n);
    hipLaunchKernelGGL(zero_kernel, dim3((n + 255) / 256), dim3(256), 0, stream, cnt, n);
    hipLaunchKernelGGL(hist_kernel, dim3((int)((m + 255) / 256)), dim3(256), 0, stream,
                       src_trg, m, n, idx64, cnt);
    hipLaunchKernelGGL(scan_kernel, dim3(1), dim3(1024), 0, stream, cnt, n, row_ptr, cursor);
    hipLaunchKernelGGL(scatter_kernel, dim3((int)((m + 255) / 256)), dim3(256), 0, stream,
                       src_trg, m, n, idx64, cursor, edge_src);
    hipLaunchKernelGGL(route_kernel, dim3((n + WPB - 1) / WPB), dim3(64 * WPB), 0, stream,
                       h, row_ptr, edge_src, out, n);
}

// Round 11
// 869.951 us; speedup vs baseline: 1.8524x; 1.8524x over previous
//
#include <hip/hip_runtime.h>
#include <math.h>

#define ROUTIT 6
#define CAP 16   // cached edges per wave: 2 waves * 16 * 64 * 8B = 16 KB/block
#define WPB 2    // waves per block in route_kernel

__device__ __forceinline__ int load_idx(const void* p, long long i, int is64)
{
    if (is64) return (int)((const long long*)p)[i];
    return ((const int*)p)[i];
}

// ---------------------------------------------------------------------------
// Cross-lane reductions on the VALU pipe only (DPP + readlane).
// dpp_add / rowsum16 verified rounds 8-10; xrow_total verified round 10.
// ---------------------------------------------------------------------------
template <int CTRL>
__device__ __forceinline__ float dpp_add(float x)
{
    int y = __builtin_amdgcn_update_dpp(0, __float_as_int(x), CTRL, 0xf, 0xf, true);
    return x + __int_as_float(y);
}

__device__ __forceinline__ float rowsum16(float p)
{
    p = dpp_add<0xB1>(p);   // quad_perm [1,0,3,2] : xor 1
    p = dpp_add<0x4E>(p);   // quad_perm [2,3,0,1] : xor 2
    p = dpp_add<0x124>(p);  // row_ror:4
    p = dpp_add<0x128>(p);  // row_ror:8
    return p;
}

// total of a row-constant value across the 4 rows, returned uniform
__device__ __forceinline__ float xrow_total(float ex)
{
    float t = dpp_add<0x142>(ex);  // row_bcast15
    t = dpp_add<0x143>(t);         // row_bcast31 -> lanes 48..63 hold total
    return __uint_as_float((unsigned)__builtin_amdgcn_readlane(__float_as_uint(t), 63));
}

__device__ __forceinline__ void edge_acc(float zx, float zy, float cx, float cy,
                                         float& a0, float& a1)
{
    float p = zx * cx + zy * cy;
    p = rowsum16(p);                    // 32-elem channel dot, |p| <= 1
    float ex = __expf(p);               // no max-subtraction needed
    float d  = xrow_total(ex);          // softmax denom over 4 channels
    float w  = ex * __builtin_amdgcn_rcpf(d);
    a0 += w * zx;
    a1 += w * zy;
}

// ---------------------------------------------------------------------------
// GEMM + per-channel L2 normalize (fp32 h) — round-8 version, verbatim.
// (Round-10 "v2" removed the xs tile and re-read x 32x from global: 2.6 GB
// fetch, VGPR 256, 11% occupancy, 889 us. Staging both tiles is right.)
// ---------------------------------------------------------------------------
__global__ __launch_bounds__(256)
void gemm_norm_kernel(const float* __restrict__ x, const float* __restrict__ W,
                      const float* __restrict__ b, float* __restrict__ h, int n)
{
    __shared__ float WT[32 * 132];    // WT[lc*132 + j] = W[j][l0+lc]
    __shared__ float xs[32 * 128];

    const int tid  = threadIdx.x;
    const int jc   = tid & 31;        // col group: cols jc*4 .. jc*4+3
    const int rg   = tid >> 5;        // row group: rows rg*4 .. rg*4+3
    const int row0 = blockIdx.x * 32;
    const int ntot = n * 128;

    for (int t = 0; t < 16; ++t) {
        int idx  = t * 256 + tid;
        int gidx = row0 * 128 + idx;
        xs[idx] = (gidx < ntot) ? x[gidx] : 0.0f;
    }

    float4 bb = ((const float4*)b)[jc];
    float acc[4][4];
    #pragma unroll
    for (int ri = 0; ri < 4; ++ri) {
        acc[ri][0] = bb.x; acc[ri][1] = bb.y; acc[ri][2] = bb.z; acc[ri][3] = bb.w;
    }

    for (int l0 = 0; l0 < 128; l0 += 32) {
        __syncthreads();
        for (int t = 0; t < 16; ++t) {
            int idx = t * 256 + tid;
            int j = idx >> 5, lc = idx & 31;
            WT[lc * 132 + j] = W[j * 128 + l0 + lc];
        }
        __syncthreads();

        #pragma unroll 8
        for (int lc = 0; lc < 32; ++lc) {
            float4 wt = ((const float4*)(WT + lc * 132))[jc];
            #pragma unroll
            for (int ri = 0; ri < 4; ++ri) {
                float xv = xs[(rg * 4 + ri) * 128 + l0 + lc];
                acc[ri][0] += xv * wt.x;
                acc[ri][1] += xv * wt.y;
                acc[ri][2] += xv * wt.z;
                acc[ri][3] += xv * wt.w;
            }
        }
    }

    #pragma unroll
    for (int ri = 0; ri < 4; ++ri) {
        float ss = acc[ri][0]*acc[ri][0] + acc[ri][1]*acc[ri][1]
                 + acc[ri][2]*acc[ri][2] + acc[ri][3]*acc[ri][3];
        ss += __shfl_xor(ss, 1);
        ss += __shfl_xor(ss, 2);
        ss += __shfl_xor(ss, 4);
        float inv = 1.0f / fmaxf(sqrtf(ss), 1e-12f);
        int row = row0 + rg * 4 + ri;
        if (row < n) {
            float4 o;
            o.x = acc[ri][0]*inv; o.y = acc[ri][1]*inv;
            o.z = acc[ri][2]*inv; o.w = acc[ri][3]*inv;
            ((float4*)(h + (size_t)row * 128))[jc] = o;
        }
    }
}

// ---------------------------------------------------------------------------
// CSR build (zero + idx-dtype detect fused into one launch)
// ---------------------------------------------------------------------------
__global__ void zero_detect_kernel(int* __restrict__ p, int n,
                                   const int* __restrict__ raw, int* __restrict__ flag)
{
    int i = blockIdx.x * blockDim.x + threadIdx.x;
    if (i < n) p[i] = 0;
    if (i == 0) {
        int all_zero = 1;
        for (int k = 1; k < 64; k += 2)
            if (raw[k] != 0) { all_zero = 0; break; }
        *flag = all_zero;   // 1 => int64 encoding, 0 => int32
    }
}

__global__ void hist_kernel(const void* __restrict__ st, long long m, int n,
                            const int* __restrict__ idx64, int* __restrict__ cnt)
{
    long long e = (long long)blockIdx.x * blockDim.x + threadIdx.x;
    if (e < m) {
        int t = load_idx(st, m + e, *idx64);
        if (t >= 0 && t < n) atomicAdd(&cnt[t], 1);
    }
}

__global__ __launch_bounds__(1024)
void scan_kernel(const int* __restrict__ cnt, int n,
                 int* __restrict__ row_ptr, int* __restrict__ cursor)
{
    __shared__ int lds[1024];
    int t = threadIdx.x;
    int per = (n + 1023) / 1024;
    int lo = min(t * per, n), hi = min(lo + per, n);
    int s = 0;
    for (int i = lo; i < hi; ++i) s += cnt[i];
    lds[t] = s;
    __syncthreads();
    for (int off = 1; off < 1024; off <<= 1) {
        int v = (t >= off) ? lds[t - off] : 0;
        __syncthreads();
        lds[t] += v;
        __syncthreads();
    }
    int run = lds[t] - s;
    for (int i = lo; i < hi; ++i) {
        row_ptr[i] = run; cursor[i] = run; run += cnt[i];
    }
    if (t == 0) row_ptr[n] = lds[1023];
}

__global__ void scatter_kernel(const void* __restrict__ st, long long m, int n,
                               const int* __restrict__ idx64,
                               int* __restrict__ cursor, int* __restrict__ edge_src)
{
    long long e = (long long)blockIdx.x * blockDim.x + threadIdx.x;
    if (e < m) {
        int is64 = *idx64;
        int t = load_idx(st, m + e, is64);
        int s = load_idx(st, e, is64);
        if (t >= 0 && t < n) {
            int pos = atomicAdd(&cursor[t], 1);
            edge_src[pos] = s;
        }
    }
}

// ---------------------------------------------------------------------------
// Routing (round-10 version): one wave per node, 6 iterations fused, c in
// registers. Iter 0 gathers + caches first CAP z-rows in LDS; iters 1..5
// replay 4-wide. Cross-lane work all-VALU except the cached ds_read_b64.
// ---------------------------------------------------------------------------
__global__ __launch_bounds__(64 * WPB)
void route_kernel(const float* __restrict__ h, const int* __restrict__ row_ptr,
                  const int* __restrict__ edge_src, float* __restrict__ out, int n)
{
    __shared__ float2 zls[WPB][CAP][64];

    int wv   = threadIdx.x >> 6;
    int wid  = __builtin_amdgcn_readfirstlane(blockIdx.x * WPB + wv);
    int lane = threadIdx.x & 63;
    if (wid >= n) return;

    const float2* __restrict__ h2 = (const float2*)h;
    float2 c0 = h2[(size_t)wid * 64 + lane];
    float cx = c0.x, cy = c0.y;

    const int e0  = row_ptr[wid], e1 = row_ptr[wid + 1];
    const int deg = e1 - e0;
    const int nc  = deg < CAP ? deg : CAP;

    // ---- iteration 0: gather, cache in LDS, compute ----
    float a0 = cx, a1 = cy;
    {
        int j = 0;
        for (; j + 1 < nc; j += 2) {
            int sa = edge_src[e0 + j];
            int sb = edge_src[e0 + j + 1];
            float2 za = h2[(size_t)sa * 64 + lane];
            float2 zb = h2[(size_t)sb * 64 + lane];
            zls[wv][j][lane] = za;
            zls[wv][j + 1][lane] = zb;
            edge_acc(za.x, za.y, cx, cy, a0, a1);
            edge_acc(zb.x, zb.y, cx, cy, a0, a1);
        }
        if (j < nc) {
            int s = edge_src[e0 + j];
            float2 z = h2[(size_t)s * 64 + lane];
            zls[wv][j][lane] = z;
            edge_acc(z.x, z.y, cx, cy, a0, a1);
        }
        for (int e = e0 + nc; e < e1; ++e) {
            int s = edge_src[e];
            float2 z = h2[(size_t)s * 64 + lane];
            edge_acc(z.x, z.y, cx, cy, a0, a1);
        }
        float ss = rowsum16(a0 * a0 + a1 * a1);
        float inv = __builtin_amdgcn_rcpf(fmaxf(sqrtf(ss), 1e-12f));
        cx = a0 * inv; cy = a1 * inv;
    }

    // ---- iterations 1..5: replay from LDS (+ uncached tail), 4-wide ILP ----
    #pragma unroll 1
    for (int it = 1; it < ROUTIT; ++it) {
        a0 = cx; a1 = cy;
        int j = 0;
        for (; j + 3 < nc; j += 4) {
            float2 z0 = zls[wv][j][lane];
            float2 z1 = zls[wv][j + 1][lane];
            float2 z2 = zls[wv][j + 2][lane];
            float2 z3 = zls[wv][j + 3][lane];
            edge_acc(z0.x, z0.y, cx, cy, a0, a1);
            edge_acc(z1.x, z1.y, cx, cy, a0, a1);
            edge_acc(z2.x, z2.y, cx, cy, a0, a1);
            edge_acc(z3.x, z3.y, cx, cy, a0, a1);
        }
        for (; j < nc; ++j) {
            float2 z = zls[wv][j][lane];
            edge_acc(z.x, z.y, cx, cy, a0, a1);
        }
        for (int e = e0 + nc; e < e1; ++e) {
            int s = edge_src[e];
            float2 z = h2[(size_t)s * 64 + lane];
            edge_acc(z.x, z.y, cx, cy, a0, a1);
        }
        float ss = rowsum16(a0 * a0 + a1 * a1);
        float inv = __builtin_amdgcn_rcpf(fmaxf(sqrtf(ss), 1e-12f));
        cx = a0 * inv; cy = a1 * inv;
    }

    float2 o; o.x = cx; o.y = cy;
    ((float2*)out)[(size_t)wid * 64 + lane] = o;
}

// ---------------------------------------------------------------------------
extern "C" void kernel_launch(void* const* d_in, const int* in_sizes, int n_in,
                              void* d_out, int out_size, void* d_ws, size_t ws_size,
                              hipStream_t stream)
{
    const float* x       = (const float*)d_in[0];
    const void*  src_trg = d_in[1];
    const float* W       = (const float*)d_in[2];
    const float* b       = (const float*)d_in[3];
    float*       out     = (float*)d_out;

    int n = in_sizes[0] / 128;
    long long m = in_sizes[1] / 2;

    // workspace layout (~59 MB)
    float* h        = (float*)d_ws;                    // n*128 floats (51.2 MB)
    int*   cnt      = (int*)(h + (size_t)n * 128);     // n
    int*   row_ptr  = cnt + n;                         // n+1
    int*   cursor   = row_ptr + (n + 1);               // n
    int*   edge_src = cursor + n;                      // m ints (6.4 MB)
    int*   idx64    = edge_src + m;                    // 1 flag

    hipLaunchKernelGGL(gemm_norm_kernel, dim3((n + 31) / 32), dim3(256), 0, stream,
                       x, W, b, h, n);
    hipLaunchKernelGGL(zero_detect_kernel, dim3((n + 255) / 256), dim3(256), 0, stream,
                       cnt, n, (const int*)src_trg, idx64);
    hipLaunchKernelGGL(hist_kernel, dim3((int)((m + 255) / 256)), dim3(256), 0, stream,
                       src_trg, m, n, idx64, cnt);
    hipLaunchKernelGGL(scan_kernel, dim3(1), dim3(1024), 0, stream, cnt, n, row_ptr, cursor);
    hipLaunchKernelGGL(scatter_kernel, dim3((int)((m + 255) / 256)), dim3(256), 0, stream,
                       src_trg, m, n, idx64, cursor, edge_src);
    hipLaunchKernelGGL(route_kernel, dim3((n + WPB - 1) / WPB), dim3(64 * WPB), 0, stream,
                       h, row_ptr, edge_src, out, n);
}

// Round 12
// 654.384 us; speedup vs baseline: 2.4627x; 1.3294x over previous
//
#include <hip/hip_runtime.h>
#include <math.h>

#define ROUTIT 6
#define CAP 16   // cached edges per wave: 2 waves * 16 * 64 * 8B = 16 KB/block
#define WPB 2    // waves per block in route_kernel
#define SCB 256  // scan blocks

__device__ __forceinline__ int load_idx(const void* p, long long i, int is64)
{
    if (is64) return (int)((const long long*)p)[i];
    return ((const int*)p)[i];
}

// ---------------------------------------------------------------------------
// Cross-lane reductions on the VALU pipe only (DPP + readlane) — verified r8-11.
// ---------------------------------------------------------------------------
template <int CTRL>
__device__ __forceinline__ float dpp_add(float x)
{
    int y = __builtin_amdgcn_update_dpp(0, __float_as_int(x), CTRL, 0xf, 0xf, true);
    return x + __int_as_float(y);
}

__device__ __forceinline__ float rowsum16(float p)
{
    p = dpp_add<0xB1>(p);   // quad_perm xor1
    p = dpp_add<0x4E>(p);   // quad_perm xor2
    p = dpp_add<0x124>(p);  // row_ror:4
    p = dpp_add<0x128>(p);  // row_ror:8
    return p;
}

__device__ __forceinline__ float xrow_total(float ex)
{
    float t = dpp_add<0x142>(ex);  // row_bcast15
    t = dpp_add<0x143>(t);         // row_bcast31 -> lanes 48..63 hold total
    return __uint_as_float((unsigned)__builtin_amdgcn_readlane(__float_as_uint(t), 63));
}

__device__ __forceinline__ void edge_acc(float zx, float zy, float cx, float cy,
                                         float& a0, float& a1)
{
    float p = zx * cx + zy * cy;
    p = rowsum16(p);                    // 32-elem channel dot, |p| <= 1
    float ex = __expf(p);
    float d  = xrow_total(ex);          // softmax denom over 4 channels
    float w  = ex * __builtin_amdgcn_rcpf(d);
    a0 += w * zx;
    a1 += w * zy;
}

// ---------------------------------------------------------------------------
// GEMM + per-channel L2 normalize (fp32 h) — round-8 version, verbatim.
// ---------------------------------------------------------------------------
__global__ __launch_bounds__(256)
void gemm_norm_kernel(const float* __restrict__ x, const float* __restrict__ W,
                      const float* __restrict__ b, float* __restrict__ h, int n)
{
    __shared__ float WT[32 * 132];
    __shared__ float xs[32 * 128];

    const int tid  = threadIdx.x;
    const int jc   = tid & 31;
    const int rg   = tid >> 5;
    const int row0 = blockIdx.x * 32;
    const int ntot = n * 128;

    for (int t = 0; t < 16; ++t) {
        int idx  = t * 256 + tid;
        int gidx = row0 * 128 + idx;
        xs[idx] = (gidx < ntot) ? x[gidx] : 0.0f;
    }

    float4 bb = ((const float4*)b)[jc];
    float acc[4][4];
    #pragma unroll
    for (int ri = 0; ri < 4; ++ri) {
        acc[ri][0] = bb.x; acc[ri][1] = bb.y; acc[ri][2] = bb.z; acc[ri][3] = bb.w;
    }

    for (int l0 = 0; l0 < 128; l0 += 32) {
        __syncthreads();
        for (int t = 0; t < 16; ++t) {
            int idx = t * 256 + tid;
            int j = idx >> 5, lc = idx & 31;
            WT[lc * 132 + j] = W[j * 128 + l0 + lc];
        }
        __syncthreads();

        #pragma unroll 8
        for (int lc = 0; lc < 32; ++lc) {
            float4 wt = ((const float4*)(WT + lc * 132))[jc];
            #pragma unroll
            for (int ri = 0; ri < 4; ++ri) {
                float xv = xs[(rg * 4 + ri) * 128 + l0 + lc];
                acc[ri][0] += xv * wt.x;
                acc[ri][1] += xv * wt.y;
                acc[ri][2] += xv * wt.z;
                acc[ri][3] += xv * wt.w;
            }
        }
    }

    #pragma unroll
    for (int ri = 0; ri < 4; ++ri) {
        float ss = acc[ri][0]*acc[ri][0] + acc[ri][1]*acc[ri][1]
                 + acc[ri][2]*acc[ri][2] + acc[ri][3]*acc[ri][3];
        ss += __shfl_xor(ss, 1);
        ss += __shfl_xor(ss, 2);
        ss += __shfl_xor(ss, 4);
        float inv = 1.0f / fmaxf(sqrtf(ss), 1e-12f);
        int row = row0 + rg * 4 + ri;
        if (row < n) {
            float4 o;
            o.x = acc[ri][0]*inv; o.y = acc[ri][1]*inv;
            o.z = acc[ri][2]*inv; o.w = acc[ri][3]*inv;
            ((float4*)(h + (size_t)row * 128))[jc] = o;
        }
    }
}

// ---------------------------------------------------------------------------
// CSR build
// ---------------------------------------------------------------------------
__global__ void zero_detect_kernel(int* __restrict__ p, int n,
                                   const int* __restrict__ raw, int* __restrict__ flag)
{
    int i = blockIdx.x * blockDim.x + threadIdx.x;
    if (i < n) p[i] = 0;
    if (i == 0) {
        int all_zero = 1;
        for (int k = 1; k < 64; k += 2)
            if (raw[k] != 0) { all_zero = 0; break; }
        *flag = all_zero;   // 1 => int64 encoding, 0 => int32
    }
}

__global__ void hist_kernel(const void* __restrict__ st, long long m, int n,
                            const int* __restrict__ idx64, int* __restrict__ cnt)
{
    long long e = (long long)blockIdx.x * blockDim.x + threadIdx.x;
    if (e < m) {
        int t = load_idx(st, m + e, *idx64);
        if (t >= 0 && t < n) atomicAdd(&cnt[t], 1);
    }
}

// ---- 3-phase parallel scan (replaces single-block scan: its stride-98
//      uncoalesced writes through ONE CU were ~250 us) ----
__global__ __launch_bounds__(256)
void scan_partial_kernel(const int* __restrict__ cnt, int n, int chunk,
                         int* __restrict__ bsum)
{
    int b = blockIdx.x, t = threadIdx.x;
    int lo = b * chunk, hi = min(lo + chunk, n);
    int s = 0;
    for (int i = lo + t; i < hi; i += 256) s += cnt[i];     // coalesced
    __shared__ int red[256];
    red[t] = s; __syncthreads();
    for (int off = 128; off > 0; off >>= 1) {
        if (t < off) red[t] += red[t + off];
        __syncthreads();
    }
    if (t == 0) bsum[b] = red[0];
}

__global__ __launch_bounds__(256)
void scan_offsets_kernel(const int* __restrict__ bsum, int nb,
                         int* __restrict__ boff, int* __restrict__ total)
{
    __shared__ int lds[256];
    int t = threadIdx.x;
    int v = (t < nb) ? bsum[t] : 0;
    lds[t] = v; __syncthreads();
    for (int off = 1; off < 256; off <<= 1) {
        int u = (t >= off) ? lds[t - off] : 0;
        __syncthreads();
        lds[t] += u;
        __syncthreads();
    }
    if (t < nb) boff[t] = lds[t] - v;      // exclusive
    if (t == 255) *total = lds[255];
}

__global__ __launch_bounds__(256)
void scan_write_kernel(const int* __restrict__ cnt, int n, int chunk,
                       const int* __restrict__ boff, const int* __restrict__ total,
                       int* __restrict__ row_ptr, int* __restrict__ cursor)
{
    int b = blockIdx.x, t = threadIdx.x;
    int lo = b * chunk, hi = min(lo + chunk, n);
    __shared__ int lds[256];
    int run = boff[b];
    for (int base = lo; base < hi; base += 256) {
        int i = base + t;
        int v = (i < hi) ? cnt[i] : 0;                       // coalesced
        lds[t] = v; __syncthreads();
        for (int off = 1; off < 256; off <<= 1) {            // inclusive scan
            int u = (t >= off) ? lds[t - off] : 0;
            __syncthreads();
            lds[t] += u;
            __syncthreads();
        }
        if (i < hi) {
            int excl = run + lds[t] - v;
            row_ptr[i] = excl;                               // coalesced
            cursor[i]  = excl;
        }
        run += lds[255];
        __syncthreads();
    }
    if (b == 0 && t == 0) row_ptr[n] = *total;
}

__global__ void scatter_kernel(const void* __restrict__ st, long long m, int n,
                               const int* __restrict__ idx64,
                               int* __restrict__ cursor, int* __restrict__ edge_src)
{
    long long e = (long long)blockIdx.x * blockDim.x + threadIdx.x;
    if (e < m) {
        int is64 = *idx64;
        int t = load_idx(st, m + e, is64);
        int s = load_idx(st, e, is64);
        if (t >= 0 && t < n) {
            int pos = atomicAdd(&cursor[t], 1);
            edge_src[pos] = s;
        }
    }
}

// ---------------------------------------------------------------------------
// Routing (round-11 version, unchanged: 410 us, VALU-bound).
// ---------------------------------------------------------------------------
__global__ __launch_bounds__(64 * WPB)
void route_kernel(const float* __restrict__ h, const int* __restrict__ row_ptr,
                  const int* __restrict__ edge_src, float* __restrict__ out, int n)
{
    __shared__ float2 zls[WPB][CAP][64];

    int wv   = threadIdx.x >> 6;
    int wid  = __builtin_amdgcn_readfirstlane(blockIdx.x * WPB + wv);
    int lane = threadIdx.x & 63;
    if (wid >= n) return;

    const float2* __restrict__ h2 = (const float2*)h;
    float2 c0 = h2[(size_t)wid * 64 + lane];
    float cx = c0.x, cy = c0.y;

    const int e0  = row_ptr[wid], e1 = row_ptr[wid + 1];
    const int deg = e1 - e0;
    const int nc  = deg < CAP ? deg : CAP;

    // ---- iteration 0: gather, cache in LDS, compute ----
    float a0 = cx, a1 = cy;
    {
        int j = 0;
        for (; j + 1 < nc; j += 2) {
            int sa = edge_src[e0 + j];
            int sb = edge_src[e0 + j + 1];
            float2 za = h2[(size_t)sa * 64 + lane];
            float2 zb = h2[(size_t)sb * 64 + lane];
            zls[wv][j][lane] = za;
            zls[wv][j + 1][lane] = zb;
            edge_acc(za.x, za.y, cx, cy, a0, a1);
            edge_acc(zb.x, zb.y, cx, cy, a0, a1);
        }
        if (j < nc) {
            int s = edge_src[e0 + j];
            float2 z = h2[(size_t)s * 64 + lane];
            zls[wv][j][lane] = z;
            edge_acc(z.x, z.y, cx, cy, a0, a1);
        }
        for (int e = e0 + nc; e < e1; ++e) {
            int s = edge_src[e];
            float2 z = h2[(size_t)s * 64 + lane];
            edge_acc(z.x, z.y, cx, cy, a0, a1);
        }
        float ss = rowsum16(a0 * a0 + a1 * a1);
        float inv = __builtin_amdgcn_rcpf(fmaxf(sqrtf(ss), 1e-12f));
        cx = a0 * inv; cy = a1 * inv;
    }

    // ---- iterations 1..5: replay from LDS (+ uncached tail), 4-wide ILP ----
    #pragma unroll 1
    for (int it = 1; it < ROUTIT; ++it) {
        a0 = cx; a1 = cy;
        int j = 0;
        for (; j + 3 < nc; j += 4) {
            float2 z0 = zls[wv][j][lane];
            float2 z1 = zls[wv][j + 1][lane];
            float2 z2 = zls[wv][j + 2][lane];
            float2 z3 = zls[wv][j + 3][lane];
            edge_acc(z0.x, z0.y, cx, cy, a0, a1);
            edge_acc(z1.x, z1.y, cx, cy, a0, a1);
            edge_acc(z2.x, z2.y, cx, cy, a0, a1);
            edge_acc(z3.x, z3.y, cx, cy, a0, a1);
        }
        for (; j < nc; ++j) {
            float2 z = zls[wv][j][lane];
            edge_acc(z.x, z.y, cx, cy, a0, a1);
        }
        for (int e = e0 + nc; e < e1; ++e) {
            int s = edge_src[e];
            float2 z = h2[(size_t)s * 64 + lane];
            edge_acc(z.x, z.y, cx, cy, a0, a1);
        }
        float ss = rowsum16(a0 * a0 + a1 * a1);
        float inv = __builtin_amdgcn_rcpf(fmaxf(sqrtf(ss), 1e-12f));
        cx = a0 * inv; cy = a1 * inv;
    }

    float2 o; o.x = cx; o.y = cy;
    ((float2*)out)[(size_t)wid * 64 + lane] = o;
}

// ---------------------------------------------------------------------------
extern "C" void kernel_launch(void* const* d_in, const int* in_sizes, int n_in,
                              void* d_out, int out_size, void* d_ws, size_t ws_size,
                              hipStream_t stream)
{
    const float* x       = (const float*)d_in[0];
    const void*  src_trg = d_in[1];
    const float* W       = (const float*)d_in[2];
    const float* b       = (const float*)d_in[3];
    float*       out     = (float*)d_out;

    int n = in_sizes[0] / 128;
    long long m = in_sizes[1] / 2;
    int chunk = (n + SCB - 1) / SCB;

    // workspace layout (~59 MB)
    float* h        = (float*)d_ws;                    // n*128 floats (51.2 MB)
    int*   cnt      = (int*)(h + (size_t)n * 128);     // n
    int*   row_ptr  = cnt + n;                         // n+1
    int*   cursor   = row_ptr + (n + 1);               // n
    int*   edge_src = cursor + n;                      // m ints (6.4 MB)
    int*   idx64    = edge_src + m;                    // 1 flag
    int*   bsum     = idx64 + 1;                       // SCB
    int*   boff     = bsum + SCB;                      // SCB
    int*   total    = boff + SCB;                      // 1

    hipLaunchKernelGGL(gemm_norm_kernel, dim3((n + 31) / 32), dim3(256), 0, stream,
                       x, W, b, h, n);
    hipLaunchKernelGGL(zero_detect_kernel, dim3((n + 255) / 256), dim3(256), 0, stream,
                       cnt, n, (const int*)src_trg, idx64);
    hipLaunchKernelGGL(hist_kernel, dim3((int)((m + 255) / 256)), dim3(256), 0, stream,
                       src_trg, m, n, idx64, cnt);
    hipLaunchKernelGGL(scan_partial_kernel, dim3(SCB), dim3(256), 0, stream,
                       cnt, n, chunk, bsum);
    hipLaunchKernelGGL(scan_offsets_kernel, dim3(1), dim3(256), 0, stream,
                       bsum, SCB, boff, total);
    hipLaunchKernelGGL(scan_write_kernel, dim3(SCB), dim3(256), 0, stream,
                       cnt, n, chunk, boff, total, row_ptr, cursor);
    hipLaunchKernelGGL(scatter_kernel, dim3((int)((m + 255) / 256)), dim3(256), 0, stream,
                       src_trg, m, n, idx64, cursor, edge_src);
    hipLaunchKernelGGL(route_kernel, dim3((n + WPB - 1) / WPB), dim3(64 * WPB), 0, stream,
                       h, row_ptr, edge_src, out, n);
}